// Round 5
// baseline (195.695 us; speedup 1.0000x reference)
//
#include <hip/hip_runtime.h>

#define SRATE 44100.0
#ifndef M_PI
#define M_PI 3.14159265358979323846
#endif

#define THREADS 256               // chunks per block
#define NBLK 2048                 // 524288 chunks / 256 (block = 8192 samples)
#define STRIDE 17                 // LDS staging row stride (floats)

// Triangular matvec: acc[r] += sum_{k < 2*(r/2)+2} M[r*10+k] * bs[k].
// A (cascade state transition) is block-lower-triangular; powers stay so.
__device__ __forceinline__ void matvec_tri(const float* __restrict__ M,
                                           const float* bs, float* acc) {
    #pragma unroll
    for (int i = 0; i < 5; i++) {
        #pragma unroll
        for (int h = 0; h < 2; h++) {
            const int r = 2*i + h;
            float a = acc[r];
            #pragma unroll
            for (int k = 0; k < 2*i + 2; k++)
                a = fmaf(M[r*10 + k], bs[k], a);
            acc[r] = a;
        }
    }
}

__device__ __forceinline__ float cascade5(const float* cb0, const float* cb1,
                                          const float* cb2, const float* ca1,
                                          const float* ca2, float* s, float u) {
    #pragma unroll
    for (int st = 0; st < 5; st++) {
        float y  = fmaf(cb0[st], u, s[2*st]);
        float t1 = fmaf(cb1[st], u, s[2*st+1]);
        s[2*st+1] = fmaf(-ca2[st], y, cb2[st] * u);
        s[2*st]   = fmaf(-ca1[st], y, t1);
        u = y;
    }
    return u;
}

// K0: coefficients + 16 fp32 matrix powers P_d = A^(32*2^d) = A^(2^(5+d)),
// d = 0..15. kA/kC use d<8 (intra-block scan + decomp); kB uses d=8..15.
__global__ __launch_bounds__(128) void k0_setup(const float* __restrict__ eqp,
                                                float* __restrict__ coef_f,
                                                float* __restrict__ mats_f) {
    __shared__ double cfd[25];
    __shared__ double Md[100];
    int t = threadIdx.x;

    if (t < 5) {
        int i = t;
        double g  = (double)eqp[i*3 + 0];
        double fc = (double)eqp[i*3 + 1];
        double q  = (double)eqp[i*3 + 2];
        double A  = pow(10.0, g / 40.0);
        double w0 = 2.0 * M_PI * (fc / SRATE);
        double al = sin(w0) / (2.0 * q);
        double c  = cos(w0);
        double b0, b1, b2, a0, a1, a2;
        if (i == 0 || i == 4) {
            double sgn = (i == 4) ? 1.0 : -1.0;
            double sA = sqrt(A);
            b0 = A * ((A + 1.0) + sgn * (A - 1.0) * c + 2.0 * sA * al);
            b1 = -2.0 * sgn * A * ((A - 1.0) + sgn * (A + 1.0) * c);
            b2 = A * ((A + 1.0) + sgn * (A - 1.0) * c - 2.0 * sA * al);
            a0 = (A + 1.0) - sgn * (A - 1.0) * c + 2.0 * sA * al;
            a1 = 2.0 * sgn * ((A - 1.0) - sgn * (A + 1.0) * c);
            a2 = (A + 1.0) - sgn * (A - 1.0) * c - 2.0 * sA * al;
        } else {
            b0 = 1.0 + al * A; b1 = -2.0 * c; b2 = 1.0 - al * A;
            a0 = 1.0 + al / A; a1 = -2.0 * c; a2 = 1.0 - al / A;
        }
        cfd[i*5+0] = b0/a0; cfd[i*5+1] = b1/a0; cfd[i*5+2] = b2/a0;
        cfd[i*5+3] = a1/a0; cfd[i*5+4] = a2/a0;
        coef_f[i*5+0] = (float)(b0/a0); coef_f[i*5+1] = (float)(b1/a0);
        coef_f[i*5+2] = (float)(b2/a0); coef_f[i*5+3] = (float)(a1/a0);
        coef_f[i*5+4] = (float)(a2/a0);
    }
    __syncthreads();

    // A: column j = one cascade step applied to unit state e_j with x=0
    if (t < 10) {
        double s[10];
        #pragma unroll
        for (int k = 0; k < 10; k++) s[k] = (k == t) ? 1.0 : 0.0;
        double u = 0.0;
        #pragma unroll
        for (int i = 0; i < 5; i++) {
            double y   = cfd[i*5+0] * u + s[2*i];
            double s1n = cfd[i*5+1] * u - cfd[i*5+3] * y + s[2*i+1];
            double s2n = cfd[i*5+2] * u - cfd[i*5+4] * y;
            s[2*i] = s1n; s[2*i+1] = s2n; u = y;
        }
        for (int r = 0; r < 10; r++) Md[r*10 + t] = s[r];
    }
    __syncthreads();

    // after k squarings Md = A^(2^k); store k = 5..20
    for (int k = 1; k <= 20; k++) {
        double val = 0.0;
        if (t < 100) {
            int r = t / 10, c = t % 10;
            #pragma unroll
            for (int j = 0; j < 10; j++) val += Md[r*10 + j] * Md[j*10 + c];
        }
        __syncthreads();
        if (t < 100) {
            Md[t] = val;
            int d = k - 5;
            if (d >= 0 && d < 16) mats_f[d*100 + t] = (float)val;
        }
        __syncthreads();
    }
}

// kA: zero-state cascade per 32-sample chunk (LDS-transposed coalesced input,
// single 17.4 KB window buffer), then 8-level Kogge-Stone over the block's 256
// chunks (triangular matvecs, LDS-broadcast mats). Writes exclusive per-chunk
// prefixes (ibuf) + block aggregate (abuf).
__global__ __launch_bounds__(256, 7) void kA(const float* __restrict__ x,
                                             const float* __restrict__ coef,
                                             const float* __restrict__ mats,
                                             float* __restrict__ ibuf,
                                             float* __restrict__ abuf) {
    __shared__ union {
        float stage[256 * STRIDE];      // 17408 B
        float buf[256][11];             // 11264 B (time-disjoint overlay)
    } sm;
    __shared__ float Mf[800];
    __shared__ float cfs[25];
    const int t = threadIdx.x, b = blockIdx.x;
    const int cb = t >> 2, q = t & 3;
    const float4* x4 = (const float4*)x + (size_t)b * 2048;

    // window 0 prefetch (flies under table loads)
    float4 rr[4];
    #pragma unroll
    for (int k = 0; k < 4; k++) rr[k] = x4[(cb + 64*k)*8 + q];

    for (int i = t; i < 800; i += 256) Mf[i] = mats[i];
    if (t < 25) cfs[t] = coef[t];

    #pragma unroll
    for (int k = 0; k < 4; k++) {
        int o = (cb + 64*k)*STRIDE + q*4;
        sm.stage[o+0]=rr[k].x; sm.stage[o+1]=rr[k].y;
        sm.stage[o+2]=rr[k].z; sm.stage[o+3]=rr[k].w;
    }
    __syncthreads();                           // stage w0 + Mf + cfs ready

    // prefetch window 1 now; completes under w0 compute
    #pragma unroll
    for (int k = 0; k < 4; k++) rr[k] = x4[(cb + 64*k)*8 + 4 + q];

    float cb0[5],cb1[5],cb2[5],ca1[5],ca2[5];
    #pragma unroll
    for (int i = 0; i < 5; i++) {
        cb0[i]=cfs[i*5+0]; cb1[i]=cfs[i*5+1]; cb2[i]=cfs[i*5+2];
        ca1[i]=cfs[i*5+3]; ca2[i]=cfs[i*5+4];
    }

    float s[10];
    #pragma unroll
    for (int k = 0; k < 10; k++) s[k] = 0.0f;

    {   // window 0: samples 0..15
        const float* row = sm.stage + t*STRIDE;
        #pragma unroll
        for (int i = 0; i < 16; i++) (void)cascade5(cb0,cb1,cb2,ca1,ca2, s, row[i]);
    }
    __syncthreads();                           // all w0 reads done
    #pragma unroll
    for (int k = 0; k < 4; k++) {
        int o = (cb + 64*k)*STRIDE + q*4;
        sm.stage[o+0]=rr[k].x; sm.stage[o+1]=rr[k].y;
        sm.stage[o+2]=rr[k].z; sm.stage[o+3]=rr[k].w;
    }
    __syncthreads();                           // stage w1 ready
    {   // window 1: samples 16..31
        const float* row = sm.stage + t*STRIDE;
        #pragma unroll
        for (int i = 0; i < 16; i++) (void)cascade5(cb0,cb1,cb2,ca1,ca2, s, row[i]);
    }
    __syncthreads();                           // stage reads done -> buf overlay safe

    // 8-level Kogge-Stone over 256 chunks
    #pragma unroll
    for (int r = 0; r < 10; r++) sm.buf[t][r] = s[r];
    __syncthreads();

    #pragma unroll 1
    for (int d = 0; d < 8; d++) {
        int src = t - (1 << d);
        int sc  = src < 0 ? 0 : src;
        float bs[10], nv[10];
        #pragma unroll
        for (int r = 0; r < 10; r++) { bs[r] = sm.buf[sc][r]; nv[r] = s[r]; }
        matvec_tri(&Mf[d*100], bs, nv);
        __syncthreads();
        bool act = src >= 0;
        #pragma unroll
        for (int r = 0; r < 10; r++) { s[r] = act ? nv[r] : s[r]; sm.buf[t][r] = s[r]; }
        __syncthreads();
    }

    #pragma unroll
    for (int r = 0; r < 10; r++)
        ibuf[(size_t)b * 2560 + r * 256 + t] = (t > 0) ? sm.buf[t-1][r] : 0.0f;
    if (t == 255) {
        #pragma unroll
        for (int r = 0; r < 10; r++) abuf[b * 10 + r] = s[r];
    }
}

// kB: one block per channel; KS scan of the channel's 256 block aggregates
// with Q_e = A^(8192*2^e) = P_{8+e}. Writes exclusive block prefixes.
__global__ __launch_bounds__(256) void kB(const float* __restrict__ mats,
                                          const float* __restrict__ abuf,
                                          float* __restrict__ bbuf) {
    __shared__ float Qf[800];
    __shared__ float buf[256][11];
    const int t = threadIdx.x, ch = blockIdx.x;
    const int g = ch * 256 + t;

    for (int i = t; i < 800; i += 256) Qf[i] = mats[800 + i];

    float v[10];
    #pragma unroll
    for (int r = 0; r < 10; r++) { v[r] = abuf[g * 10 + r]; buf[t][r] = v[r]; }
    __syncthreads();

    #pragma unroll 1
    for (int e = 0; e < 8; e++) {
        int src = t - (1 << e);
        int sc  = src < 0 ? 0 : src;
        float bs[10], nv[10];
        #pragma unroll
        for (int r = 0; r < 10; r++) { bs[r] = buf[sc][r]; nv[r] = v[r]; }
        matvec_tri(&Qf[e*100], bs, nv);
        __syncthreads();
        bool act = src >= 0;
        #pragma unroll
        for (int r = 0; r < 10; r++) { v[r] = act ? nv[r] : v[r]; buf[t][r] = v[r]; }
        __syncthreads();
    }

    #pragma unroll
    for (int r = 0; r < 10; r++)
        bbuf[g * 10 + r] = (t > 0) ? buf[t-1][r] : 0.0f;
}

// kC: init = ibuf[chunk] + A^(32*t)*bbuf[block] (8 triangular decomp matvecs),
// re-run cascade. Window-0 outputs are captured (transposed) into registers so
// that each 128B output line's two 64B halves are stored BACK-TO-BACK at the
// end -> L2 merges them into full-line evictions (kills the 1.48x write tax).
__global__ __launch_bounds__(256, 7) void kC(const float* __restrict__ x,
                                             const float* __restrict__ coef,
                                             const float* __restrict__ mats,
                                             const float* __restrict__ ibuf,
                                             const float* __restrict__ bbuf,
                                             float* __restrict__ out) {
    __shared__ float stage[256 * STRIDE];      // 17408 B, in+out reuse
    __shared__ float Mf[800];
    __shared__ float cfs[25];
    const int t = threadIdx.x, b = blockIdx.x;
    const int cb = t >> 2, q = t & 3;
    const float4* x4 = (const float4*)x + (size_t)b * 2048;
    float4* o4 = (float4*)out + (size_t)b * 2048;

    float4 rr[4];
    #pragma unroll
    for (int k = 0; k < 4; k++) rr[k] = x4[(cb + 64*k)*8 + q];

    float sp[10];
    #pragma unroll
    for (int r = 0; r < 10; r++) sp[r] = ibuf[(size_t)b * 2560 + r * 256 + t];
    float bp[10];
    #pragma unroll
    for (int r = 0; r < 10; r++) bp[r] = bbuf[b * 10 + r];

    for (int i = t; i < 800; i += 256) Mf[i] = mats[i];
    if (t < 25) cfs[t] = coef[t];

    #pragma unroll
    for (int k = 0; k < 4; k++) {
        int o = (cb + 64*k)*STRIDE + q*4;
        stage[o+0]=rr[k].x; stage[o+1]=rr[k].y;
        stage[o+2]=rr[k].z; stage[o+3]=rr[k].w;
    }
    __syncthreads();                           // B1: stage w0 + Mf + cfs ready

    // prefetch window 1; completes under decomp + w0 compute
    #pragma unroll
    for (int k = 0; k < 4; k++) rr[k] = x4[(cb + 64*k)*8 + 4 + q];

    float cb0[5],cb1[5],cb2[5],ca1[5],ca2[5];
    #pragma unroll
    for (int i = 0; i < 5; i++) {
        cb0[i]=cfs[i*5+0]; cb1[i]=cfs[i*5+1]; cb2[i]=cfs[i*5+2];
        ca1[i]=cfs[i*5+3]; ca2[i]=cfs[i*5+4];
    }

    // binary decomposition: bp = A^(32*t) * Bpre
    #pragma unroll 1
    for (int d = 0; d < 8; d++) {
        float wv[10];
        #pragma unroll
        for (int r = 0; r < 10; r++) wv[r] = 0.0f;
        matvec_tri(&Mf[d*100], bp, wv);
        bool bit = (t >> d) & 1;
        #pragma unroll
        for (int r = 0; r < 10; r++) bp[r] = bit ? wv[r] : bp[r];
    }
    float s[10];
    #pragma unroll
    for (int r = 0; r < 10; r++) s[r] = sp[r] + bp[r];

    {   // window 0: compute in place
        float* row = stage + t*STRIDE;
        #pragma unroll
        for (int i = 0; i < 16; i++) row[i] = cascade5(cb0,cb1,cb2,ca1,ca2, s, row[i]);
    }
    __syncthreads();                           // B2: y0 rows complete

    // capture w0 transposed output into registers (deferred store)
    float4 y0[4];
    #pragma unroll
    for (int k = 0; k < 4; k++) {
        int o = (cb + 64*k)*STRIDE + q*4;
        y0[k] = make_float4(stage[o+0], stage[o+1], stage[o+2], stage[o+3]);
    }
    __syncthreads();                           // B3: captures done -> overwrite safe

    #pragma unroll
    for (int k = 0; k < 4; k++) {
        int o = (cb + 64*k)*STRIDE + q*4;
        stage[o+0]=rr[k].x; stage[o+1]=rr[k].y;
        stage[o+2]=rr[k].z; stage[o+3]=rr[k].w;
    }
    __syncthreads();                           // B4: stage w1 ready

    {   // window 1: compute in place
        float* row = stage + t*STRIDE;
        #pragma unroll
        for (int i = 0; i < 16; i++) row[i] = cascade5(cb0,cb1,cb2,ca1,ca2, s, row[i]);
    }
    __syncthreads();                           // B5: y1 rows complete

    // paired stores: both 64B halves of each 128B line, back-to-back
    #pragma unroll
    for (int k = 0; k < 4; k++) {
        int o = (cb + 64*k)*STRIDE + q*4;
        o4[(cb + 64*k)*8 + q]     = y0[k];
        o4[(cb + 64*k)*8 + 4 + q] = make_float4(stage[o+0], stage[o+1],
                                                stage[o+2], stage[o+3]);
    }
}

extern "C" void kernel_launch(void* const* d_in, const int* in_sizes, int n_in,
                              void* d_out, int out_size, void* d_ws, size_t ws_size,
                              hipStream_t stream) {
    const float* x   = (const float*)d_in[0];
    const float* eqp = (const float*)d_in[1];
    float* out = (float*)d_out;
    char* ws = (char*)d_ws;

    float* coef_f = (float*)ws;                              // 25 floats
    float* mats_f = (float*)(ws + 256);                      // 1600 floats
    float* ibuf   = (float*)(ws + 8192);                     // 2048*2560 fl = 20.97 MB
    float* abuf   = (float*)(ws + 8192 + 20971520);          // 2048*10 floats
    float* bbuf   = (float*)(ws + 8192 + 20971520 + 81920);  // 2048*10 floats

    hipLaunchKernelGGL(k0_setup, dim3(1), dim3(128), 0, stream, eqp, coef_f, mats_f);
    hipLaunchKernelGGL(kA, dim3(NBLK), dim3(THREADS), 0, stream, x, coef_f, mats_f, ibuf, abuf);
    hipLaunchKernelGGL(kB, dim3(8),    dim3(THREADS), 0, stream, mats_f, abuf, bbuf);
    hipLaunchKernelGGL(kC, dim3(NBLK), dim3(THREADS), 0, stream,
                       x, coef_f, mats_f, ibuf, bbuf, out);
}

// Round 6
// 191.572 us; speedup vs baseline: 1.0215x; 1.0215x over previous
//
#include <hip/hip_runtime.h>

#define SRATE 44100.0
#ifndef M_PI
#define M_PI 3.14159265358979323846
#endif

#define THREADS 256               // chunks per block
#define NBLK 2048                 // 524288 chunks / 256 (block = 8192 samples)
#define STRIDE 17                 // LDS staging row stride (floats)

// Triangular matvec: acc[r] += sum_{k < 2*(r/2)+2} M[r*10+k] * bs[k].
// A (cascade state transition) is block-lower-triangular; powers stay so.
__device__ __forceinline__ void matvec_tri(const float* __restrict__ M,
                                           const float* bs, float* acc) {
    #pragma unroll
    for (int i = 0; i < 5; i++) {
        #pragma unroll
        for (int h = 0; h < 2; h++) {
            const int r = 2*i + h;
            float a = acc[r];
            #pragma unroll
            for (int k = 0; k < 2*i + 2; k++)
                a = fmaf(M[r*10 + k], bs[k], a);
            acc[r] = a;
        }
    }
}

__device__ __forceinline__ float cascade5(const float* cb0, const float* cb1,
                                          const float* cb2, const float* ca1,
                                          const float* ca2, float* s, float u) {
    #pragma unroll
    for (int st = 0; st < 5; st++) {
        float y  = fmaf(cb0[st], u, s[2*st]);
        float t1 = fmaf(cb1[st], u, s[2*st+1]);
        s[2*st+1] = fmaf(-ca2[st], y, cb2[st] * u);
        s[2*st]   = fmaf(-ca1[st], y, t1);
        u = y;
    }
    return u;
}

// K0: coefficients + 16 fp32 matrix powers P_d = A^(32*2^d) = A^(2^(5+d)),
// d = 0..15. kA/kC use d<8 (tree/scan/decomp); kB uses d=8..15.
__global__ __launch_bounds__(128) void k0_setup(const float* __restrict__ eqp,
                                                float* __restrict__ coef_f,
                                                float* __restrict__ mats_f) {
    __shared__ double cfd[25];
    __shared__ double Md[100];
    int t = threadIdx.x;

    if (t < 5) {
        int i = t;
        double g  = (double)eqp[i*3 + 0];
        double fc = (double)eqp[i*3 + 1];
        double q  = (double)eqp[i*3 + 2];
        double A  = pow(10.0, g / 40.0);
        double w0 = 2.0 * M_PI * (fc / SRATE);
        double al = sin(w0) / (2.0 * q);
        double c  = cos(w0);
        double b0, b1, b2, a0, a1, a2;
        if (i == 0 || i == 4) {
            double sgn = (i == 4) ? 1.0 : -1.0;
            double sA = sqrt(A);
            b0 = A * ((A + 1.0) + sgn * (A - 1.0) * c + 2.0 * sA * al);
            b1 = -2.0 * sgn * A * ((A - 1.0) + sgn * (A + 1.0) * c);
            b2 = A * ((A + 1.0) + sgn * (A - 1.0) * c - 2.0 * sA * al);
            a0 = (A + 1.0) - sgn * (A - 1.0) * c + 2.0 * sA * al;
            a1 = 2.0 * sgn * ((A - 1.0) - sgn * (A + 1.0) * c);
            a2 = (A + 1.0) - sgn * (A - 1.0) * c - 2.0 * sA * al;
        } else {
            b0 = 1.0 + al * A; b1 = -2.0 * c; b2 = 1.0 - al * A;
            a0 = 1.0 + al / A; a1 = -2.0 * c; a2 = 1.0 - al / A;
        }
        cfd[i*5+0] = b0/a0; cfd[i*5+1] = b1/a0; cfd[i*5+2] = b2/a0;
        cfd[i*5+3] = a1/a0; cfd[i*5+4] = a2/a0;
        coef_f[i*5+0] = (float)(b0/a0); coef_f[i*5+1] = (float)(b1/a0);
        coef_f[i*5+2] = (float)(b2/a0); coef_f[i*5+3] = (float)(a1/a0);
        coef_f[i*5+4] = (float)(a2/a0);
    }
    __syncthreads();

    if (t < 10) {
        double s[10];
        #pragma unroll
        for (int k = 0; k < 10; k++) s[k] = (k == t) ? 1.0 : 0.0;
        double u = 0.0;
        #pragma unroll
        for (int i = 0; i < 5; i++) {
            double y   = cfd[i*5+0] * u + s[2*i];
            double s1n = cfd[i*5+1] * u - cfd[i*5+3] * y + s[2*i+1];
            double s2n = cfd[i*5+2] * u - cfd[i*5+4] * y;
            s[2*i] = s1n; s[2*i+1] = s2n; u = y;
        }
        for (int r = 0; r < 10; r++) Md[r*10 + t] = s[r];
    }
    __syncthreads();

    for (int k = 1; k <= 20; k++) {
        double val = 0.0;
        if (t < 100) {
            int r = t / 10, c = t % 10;
            #pragma unroll
            for (int j = 0; j < 10; j++) val += Md[r*10 + j] * Md[j*10 + c];
        }
        __syncthreads();
        if (t < 100) {
            Md[t] = val;
            int d = k - 5;
            if (d >= 0 && d < 16) mats_f[d*100 + t] = (float)val;
        }
        __syncthreads();
    }
}

// kA: zero-state cascade per 32-sample chunk (both windows LDS-staged up
// front), then an 8-level TREE REDUCE to the block aggregate only.
// Writes 10 floats per block (abuf). No per-chunk prefix output.
__global__ __launch_bounds__(256, 4) void kA(const float* __restrict__ x,
                                             const float* __restrict__ coef,
                                             const float* __restrict__ mats,
                                             float* __restrict__ abuf) {
    __shared__ union {
        float s0[256 * STRIDE];         // 17408 B (window 0)
        float buf[256][11];             // 11264 B (time-disjoint overlay)
    } smA;
    __shared__ float s1[256 * STRIDE];  // 17408 B (window 1)
    __shared__ float Mf[800];
    __shared__ float cfs[25];
    const int t = threadIdx.x, b = blockIdx.x;
    const int cb = t >> 2, q = t & 3;
    const float4* x4 = (const float4*)x + (size_t)b * 2048;

    float4 rr[4], rr2[4];
    #pragma unroll
    for (int k = 0; k < 4; k++) rr[k]  = x4[(cb + 64*k)*8 + q];
    #pragma unroll
    for (int k = 0; k < 4; k++) rr2[k] = x4[(cb + 64*k)*8 + 4 + q];

    for (int i = t; i < 800; i += 256) Mf[i] = mats[i];
    if (t < 25) cfs[t] = coef[t];

    #pragma unroll
    for (int k = 0; k < 4; k++) {
        int o = (cb + 64*k)*STRIDE + q*4;
        smA.s0[o+0]=rr[k].x; smA.s0[o+1]=rr[k].y;
        smA.s0[o+2]=rr[k].z; smA.s0[o+3]=rr[k].w;
    }
    __syncthreads();                           // B1: s0 + Mf + cfs ready

    // stage w1 while others compute w0 (disjoint LDS)
    #pragma unroll
    for (int k = 0; k < 4; k++) {
        int o = (cb + 64*k)*STRIDE + q*4;
        s1[o+0]=rr2[k].x; s1[o+1]=rr2[k].y;
        s1[o+2]=rr2[k].z; s1[o+3]=rr2[k].w;
    }

    float cb0[5],cb1[5],cb2[5],ca1[5],ca2[5];
    #pragma unroll
    for (int i = 0; i < 5; i++) {
        cb0[i]=cfs[i*5+0]; cb1[i]=cfs[i*5+1]; cb2[i]=cfs[i*5+2];
        ca1[i]=cfs[i*5+3]; ca2[i]=cfs[i*5+4];
    }

    float s[10];
    #pragma unroll
    for (int k = 0; k < 10; k++) s[k] = 0.0f;

    {   const float* row = smA.s0 + t*STRIDE;
        #pragma unroll
        for (int i = 0; i < 16; i++) (void)cascade5(cb0,cb1,cb2,ca1,ca2, s, row[i]);
    }
    __syncthreads();                           // B2: s1 staged; s0 reads done
    {   const float* row = s1 + t*STRIDE;
        #pragma unroll
        for (int i = 0; i < 16; i++) (void)cascade5(cb0,cb1,cb2,ca1,ca2, s, row[i]);
    }

    // tree reduce to block aggregate (buf overlays s0)
    #pragma unroll
    for (int r = 0; r < 10; r++) smA.buf[t][r] = s[r];
    __syncthreads();                           // B3

    #pragma unroll 1
    for (int d = 0; d < 8; d++) {
        const int span = 2 << d;
        if (((t + 1) & (span - 1)) == 0) {     // end of a combined pair
            const int partner = t - (1 << d);
            float bs[10];
            #pragma unroll
            for (int r = 0; r < 10; r++) bs[r] = smA.buf[partner][r];
            matvec_tri(&Mf[d*100], bs, s);     // s = s + P_d * B_left
            #pragma unroll
            for (int r = 0; r < 10; r++) smA.buf[t][r] = s[r];
        }
        __syncthreads();
    }

    if (t == 255) {
        #pragma unroll
        for (int r = 0; r < 10; r++) abuf[b * 10 + r] = s[r];
    }
}

// kB: one block per channel; KS scan of the channel's 256 block aggregates
// with Q_e = A^(8192*2^e) = P_{8+e}. Writes exclusive block prefixes.
__global__ __launch_bounds__(256) void kB(const float* __restrict__ mats,
                                          const float* __restrict__ abuf,
                                          float* __restrict__ bbuf) {
    __shared__ float Qf[800];
    __shared__ float buf[256][11];
    const int t = threadIdx.x, ch = blockIdx.x;
    const int g = ch * 256 + t;

    for (int i = t; i < 800; i += 256) Qf[i] = mats[800 + i];

    float v[10];
    #pragma unroll
    for (int r = 0; r < 10; r++) { v[r] = abuf[g * 10 + r]; buf[t][r] = v[r]; }
    __syncthreads();

    #pragma unroll 1
    for (int e = 0; e < 8; e++) {
        int src = t - (1 << e);
        int sc  = src < 0 ? 0 : src;
        float bs[10], nv[10];
        #pragma unroll
        for (int r = 0; r < 10; r++) { bs[r] = buf[sc][r]; nv[r] = v[r]; }
        matvec_tri(&Qf[e*100], bs, nv);
        __syncthreads();
        bool act = src >= 0;
        #pragma unroll
        for (int r = 0; r < 10; r++) { v[r] = act ? nv[r] : v[r]; buf[t][r] = v[r]; }
        __syncthreads();
    }

    #pragma unroll
    for (int r = 0; r < 10; r++)
        bbuf[g * 10 + r] = (t > 0) ? buf[t-1][r] : 0.0f;
}

// kC: stages both windows, runs the zero-state cascade (keeping the 32 input
// samples in registers), does the intra-block KS scan itself (no ibuf),
// computes true init = local_prefix + A^(32*t)*bbuf[b], re-runs the cascade
// in registers, and stores via a FULL-LINE transposed coop-store: every store
// instruction writes 8 complete 128B lines (1 KB contiguous per wave).
__global__ __launch_bounds__(256, 4) void kC(const float* __restrict__ x,
                                             const float* __restrict__ coef,
                                             const float* __restrict__ mats,
                                             const float* __restrict__ bbuf,
                                             float* __restrict__ out) {
    __shared__ union {
        float s0[256 * STRIDE];
        float buf[256][11];
    } smA;
    __shared__ float s1[256 * STRIDE];
    __shared__ float Mf[800];
    __shared__ float cfs[25];
    const int t = threadIdx.x, b = blockIdx.x;
    const int cb = t >> 2, q = t & 3;
    const float4* x4 = (const float4*)x + (size_t)b * 2048;
    float4* o4 = (float4*)out + (size_t)b * 2048;

    float4 rr[4], rr2[4];
    #pragma unroll
    for (int k = 0; k < 4; k++) rr[k]  = x4[(cb + 64*k)*8 + q];
    #pragma unroll
    for (int k = 0; k < 4; k++) rr2[k] = x4[(cb + 64*k)*8 + 4 + q];

    for (int i = t; i < 800; i += 256) Mf[i] = mats[i];
    if (t < 25) cfs[t] = coef[t];

    float bp[10];
    #pragma unroll
    for (int r = 0; r < 10; r++) bp[r] = bbuf[b * 10 + r];

    #pragma unroll
    for (int k = 0; k < 4; k++) {
        int o = (cb + 64*k)*STRIDE + q*4;
        smA.s0[o+0]=rr[k].x; smA.s0[o+1]=rr[k].y;
        smA.s0[o+2]=rr[k].z; smA.s0[o+3]=rr[k].w;
    }
    __syncthreads();                           // B1: s0 + Mf + cfs ready

    #pragma unroll
    for (int k = 0; k < 4; k++) {
        int o = (cb + 64*k)*STRIDE + q*4;
        s1[o+0]=rr2[k].x; s1[o+1]=rr2[k].y;
        s1[o+2]=rr2[k].z; s1[o+3]=rr2[k].w;
    }

    float cb0[5],cb1[5],cb2[5],ca1[5],ca2[5];
    #pragma unroll
    for (int i = 0; i < 5; i++) {
        cb0[i]=cfs[i*5+0]; cb1[i]=cfs[i*5+1]; cb2[i]=cfs[i*5+2];
        ca1[i]=cfs[i*5+3]; ca2[i]=cfs[i*5+4];
    }

    // zero-state cascade, stashing input samples in registers
    float xw0[16], xw1[16];
    float s[10];
    #pragma unroll
    for (int k = 0; k < 10; k++) s[k] = 0.0f;
    {   const float* row = smA.s0 + t*STRIDE;
        #pragma unroll
        for (int i = 0; i < 16; i++) { xw0[i] = row[i]; (void)cascade5(cb0,cb1,cb2,ca1,ca2, s, xw0[i]); }
    }
    __syncthreads();                           // B2: s1 staged; s0 reads done
    {   const float* row = s1 + t*STRIDE;
        #pragma unroll
        for (int i = 0; i < 16; i++) { xw1[i] = row[i]; (void)cascade5(cb0,cb1,cb2,ca1,ca2, s, xw1[i]); }
    }

    // intra-block KS scan (buf overlays s0)
    #pragma unroll
    for (int r = 0; r < 10; r++) smA.buf[t][r] = s[r];
    __syncthreads();                           // B3

    #pragma unroll 1
    for (int d = 0; d < 8; d++) {
        int src = t - (1 << d);
        int sc  = src < 0 ? 0 : src;
        float bs[10], nv[10];
        #pragma unroll
        for (int r = 0; r < 10; r++) { bs[r] = smA.buf[sc][r]; nv[r] = s[r]; }
        matvec_tri(&Mf[d*100], bs, nv);
        __syncthreads();
        bool act = src >= 0;
        #pragma unroll
        for (int r = 0; r < 10; r++) { s[r] = act ? nv[r] : s[r]; smA.buf[t][r] = s[r]; }
        __syncthreads();
    }

    float sp[10];
    #pragma unroll
    for (int r = 0; r < 10; r++) sp[r] = (t > 0) ? smA.buf[t-1][r] : 0.0f;

    // binary decomposition: bp = A^(32*t) * Bpre
    #pragma unroll 1
    for (int d = 0; d < 8; d++) {
        float wv[10];
        #pragma unroll
        for (int r = 0; r < 10; r++) wv[r] = 0.0f;
        matvec_tri(&Mf[d*100], bp, wv);
        bool bit = (t >> d) & 1;
        #pragma unroll
        for (int r = 0; r < 10; r++) bp[r] = bit ? wv[r] : bp[r];
    }
    #pragma unroll
    for (int r = 0; r < 10; r++) s[r] = sp[r] + bp[r];
    __syncthreads();                           // B4: buf reads done -> s0 free

    // final cascade, register-resident
    #pragma unroll
    for (int i = 0; i < 16; i++) xw0[i] = cascade5(cb0,cb1,cb2,ca1,ca2, s, xw0[i]);
    #pragma unroll
    for (int i = 0; i < 16; i++) xw1[i] = cascade5(cb0,cb1,cb2,ca1,ca2, s, xw1[i]);

    // stage y transposed
    {   float* row = smA.s0 + t*STRIDE;
        #pragma unroll
        for (int i = 0; i < 16; i++) row[i] = xw0[i];
    }
    {   float* row = s1 + t*STRIDE;
        #pragma unroll
        for (int i = 0; i < 16; i++) row[i] = xw1[i];
    }
    __syncthreads();                           // B5: y staged

    // full-line coop store: chunk = c2 + 32*kk, piece p = t&7 (8 x 16B = 128B)
    const int c2 = t >> 3, p = t & 7, pq = p & 3;
    const float* srcb = (p < 4) ? smA.s0 : s1;
    #pragma unroll
    for (int kk = 0; kk < 8; kk++) {
        int chunk = c2 + 32*kk;
        int o = chunk*STRIDE + pq*4;
        o4[chunk*8 + p] = make_float4(srcb[o+0], srcb[o+1], srcb[o+2], srcb[o+3]);
    }
}

extern "C" void kernel_launch(void* const* d_in, const int* in_sizes, int n_in,
                              void* d_out, int out_size, void* d_ws, size_t ws_size,
                              hipStream_t stream) {
    const float* x   = (const float*)d_in[0];
    const float* eqp = (const float*)d_in[1];
    float* out = (float*)d_out;
    char* ws = (char*)d_ws;

    float* coef_f = (float*)ws;                              // 25 floats
    float* mats_f = (float*)(ws + 256);                      // 1600 floats
    float* abuf   = (float*)(ws + 8192);                     // 2048*10 floats
    float* bbuf   = (float*)(ws + 8192 + 81920);             // 2048*10 floats

    hipLaunchKernelGGL(k0_setup, dim3(1), dim3(128), 0, stream, eqp, coef_f, mats_f);
    hipLaunchKernelGGL(kA, dim3(NBLK), dim3(THREADS), 0, stream, x, coef_f, mats_f, abuf);
    hipLaunchKernelGGL(kB, dim3(8),    dim3(THREADS), 0, stream, mats_f, abuf, bbuf);
    hipLaunchKernelGGL(kC, dim3(NBLK), dim3(THREADS), 0, stream,
                       x, coef_f, mats_f, bbuf, out);
}

// Round 7
// 176.918 us; speedup vs baseline: 1.1061x; 1.0828x over previous
//
#include <hip/hip_runtime.h>

#define SRATE 44100.0
#ifndef M_PI
#define M_PI 3.14159265358979323846
#endif

#define THREADS 256               // chunks per block
#define NBLK 2048                 // 524288 chunks / 256 (block = 8192 samples)
#define STRIDE 17                 // kA staging row stride (floats)
#define CSTRIDE 33                // kC staging row stride (32 samples + 1 pad)

// Triangular matvec: acc[r] += sum_{k < 2*(r/2)+2} M[r*10+k] * bs[k].
// A (cascade state transition) is block-lower-triangular; powers stay so.
__device__ __forceinline__ void matvec_tri(const float* __restrict__ M,
                                           const float* bs, float* acc) {
    #pragma unroll
    for (int i = 0; i < 5; i++) {
        #pragma unroll
        for (int h = 0; h < 2; h++) {
            const int r = 2*i + h;
            float a = acc[r];
            #pragma unroll
            for (int k = 0; k < 2*i + 2; k++)
                a = fmaf(M[r*10 + k], bs[k], a);
            acc[r] = a;
        }
    }
}

__device__ __forceinline__ float cascade5(const float* cb0, const float* cb1,
                                          const float* cb2, const float* ca1,
                                          const float* ca2, float* s, float u) {
    #pragma unroll
    for (int st = 0; st < 5; st++) {
        float y  = fmaf(cb0[st], u, s[2*st]);
        float t1 = fmaf(cb1[st], u, s[2*st+1]);
        s[2*st+1] = fmaf(-ca2[st], y, cb2[st] * u);
        s[2*st]   = fmaf(-ca1[st], y, t1);
        u = y;
    }
    return u;
}

// K0: coefficients + 16 fp32 matrix powers P_d = A^(32*2^d) = A^(2^(5+d)),
// d = 0..15. kA/kC use d<8 (scan + decomp); kB uses d=8..15.
__global__ __launch_bounds__(128) void k0_setup(const float* __restrict__ eqp,
                                                float* __restrict__ coef_f,
                                                float* __restrict__ mats_f) {
    __shared__ double cfd[25];
    __shared__ double Md[100];
    int t = threadIdx.x;

    if (t < 5) {
        int i = t;
        double g  = (double)eqp[i*3 + 0];
        double fc = (double)eqp[i*3 + 1];
        double q  = (double)eqp[i*3 + 2];
        double A  = pow(10.0, g / 40.0);
        double w0 = 2.0 * M_PI * (fc / SRATE);
        double al = sin(w0) / (2.0 * q);
        double c  = cos(w0);
        double b0, b1, b2, a0, a1, a2;
        if (i == 0 || i == 4) {
            double sgn = (i == 4) ? 1.0 : -1.0;
            double sA = sqrt(A);
            b0 = A * ((A + 1.0) + sgn * (A - 1.0) * c + 2.0 * sA * al);
            b1 = -2.0 * sgn * A * ((A - 1.0) + sgn * (A + 1.0) * c);
            b2 = A * ((A + 1.0) + sgn * (A - 1.0) * c - 2.0 * sA * al);
            a0 = (A + 1.0) - sgn * (A - 1.0) * c + 2.0 * sA * al;
            a1 = 2.0 * sgn * ((A - 1.0) - sgn * (A + 1.0) * c);
            a2 = (A + 1.0) - sgn * (A - 1.0) * c - 2.0 * sA * al;
        } else {
            b0 = 1.0 + al * A; b1 = -2.0 * c; b2 = 1.0 - al * A;
            a0 = 1.0 + al / A; a1 = -2.0 * c; a2 = 1.0 - al / A;
        }
        cfd[i*5+0] = b0/a0; cfd[i*5+1] = b1/a0; cfd[i*5+2] = b2/a0;
        cfd[i*5+3] = a1/a0; cfd[i*5+4] = a2/a0;
        coef_f[i*5+0] = (float)(b0/a0); coef_f[i*5+1] = (float)(b1/a0);
        coef_f[i*5+2] = (float)(b2/a0); coef_f[i*5+3] = (float)(a1/a0);
        coef_f[i*5+4] = (float)(a2/a0);
    }
    __syncthreads();

    if (t < 10) {
        double s[10];
        #pragma unroll
        for (int k = 0; k < 10; k++) s[k] = (k == t) ? 1.0 : 0.0;
        double u = 0.0;
        #pragma unroll
        for (int i = 0; i < 5; i++) {
            double y   = cfd[i*5+0] * u + s[2*i];
            double s1n = cfd[i*5+1] * u - cfd[i*5+3] * y + s[2*i+1];
            double s2n = cfd[i*5+2] * u - cfd[i*5+4] * y;
            s[2*i] = s1n; s[2*i+1] = s2n; u = y;
        }
        for (int r = 0; r < 10; r++) Md[r*10 + t] = s[r];
    }
    __syncthreads();

    for (int k = 1; k <= 20; k++) {
        double val = 0.0;
        if (t < 100) {
            int r = t / 10, c = t % 10;
            #pragma unroll
            for (int j = 0; j < 10; j++) val += Md[r*10 + j] * Md[j*10 + c];
        }
        __syncthreads();
        if (t < 100) {
            Md[t] = val;
            int d = k - 5;
            if (d >= 0 && d < 16) mats_f[d*100 + t] = (float)val;
        }
        __syncthreads();
    }
}

// kA: zero-state cascade per 32-sample chunk (LDS-transposed coalesced input,
// single 17.4 KB window buffer), then 8-level Kogge-Stone over the block's 256
// chunks (triangular matvecs, LDS-broadcast mats). Writes exclusive per-chunk
// prefixes (ibuf, full-line coalesced) + block aggregate (abuf).
__global__ __launch_bounds__(256, 7) void kA(const float* __restrict__ x,
                                             const float* __restrict__ coef,
                                             const float* __restrict__ mats,
                                             float* __restrict__ ibuf,
                                             float* __restrict__ abuf) {
    __shared__ union {
        float stage[256 * STRIDE];      // 17408 B
        float buf[256][11];             // 11264 B (time-disjoint overlay)
    } sm;
    __shared__ float Mf[800];
    __shared__ float cfs[25];
    const int t = threadIdx.x, b = blockIdx.x;
    const int cb = t >> 2, q = t & 3;
    const float4* x4 = (const float4*)x + (size_t)b * 2048;

    // window 0 prefetch (flies under table loads)
    float4 rr[4];
    #pragma unroll
    for (int k = 0; k < 4; k++) rr[k] = x4[(cb + 64*k)*8 + q];

    for (int i = t; i < 800; i += 256) Mf[i] = mats[i];
    if (t < 25) cfs[t] = coef[t];

    #pragma unroll
    for (int k = 0; k < 4; k++) {
        int o = (cb + 64*k)*STRIDE + q*4;
        sm.stage[o+0]=rr[k].x; sm.stage[o+1]=rr[k].y;
        sm.stage[o+2]=rr[k].z; sm.stage[o+3]=rr[k].w;
    }
    __syncthreads();                           // stage w0 + Mf + cfs ready

    // prefetch window 1 now; completes under w0 compute
    #pragma unroll
    for (int k = 0; k < 4; k++) rr[k] = x4[(cb + 64*k)*8 + 4 + q];

    float cb0[5],cb1[5],cb2[5],ca1[5],ca2[5];
    #pragma unroll
    for (int i = 0; i < 5; i++) {
        cb0[i]=cfs[i*5+0]; cb1[i]=cfs[i*5+1]; cb2[i]=cfs[i*5+2];
        ca1[i]=cfs[i*5+3]; ca2[i]=cfs[i*5+4];
    }

    float s[10];
    #pragma unroll
    for (int k = 0; k < 10; k++) s[k] = 0.0f;

    {   // window 0: samples 0..15
        const float* row = sm.stage + t*STRIDE;
        #pragma unroll
        for (int i = 0; i < 16; i++) (void)cascade5(cb0,cb1,cb2,ca1,ca2, s, row[i]);
    }
    __syncthreads();                           // all w0 reads done
    #pragma unroll
    for (int k = 0; k < 4; k++) {
        int o = (cb + 64*k)*STRIDE + q*4;
        sm.stage[o+0]=rr[k].x; sm.stage[o+1]=rr[k].y;
        sm.stage[o+2]=rr[k].z; sm.stage[o+3]=rr[k].w;
    }
    __syncthreads();                           // stage w1 ready
    {   // window 1: samples 16..31
        const float* row = sm.stage + t*STRIDE;
        #pragma unroll
        for (int i = 0; i < 16; i++) (void)cascade5(cb0,cb1,cb2,ca1,ca2, s, row[i]);
    }
    __syncthreads();                           // stage reads done -> buf overlay safe

    // 8-level Kogge-Stone over 256 chunks
    #pragma unroll
    for (int r = 0; r < 10; r++) sm.buf[t][r] = s[r];
    __syncthreads();

    #pragma unroll 1
    for (int d = 0; d < 8; d++) {
        int src = t - (1 << d);
        int sc  = src < 0 ? 0 : src;
        float bs[10], nv[10];
        #pragma unroll
        for (int r = 0; r < 10; r++) { bs[r] = sm.buf[sc][r]; nv[r] = s[r]; }
        matvec_tri(&Mf[d*100], bs, nv);
        __syncthreads();
        bool act = src >= 0;
        #pragma unroll
        for (int r = 0; r < 10; r++) { s[r] = act ? nv[r] : s[r]; sm.buf[t][r] = s[r]; }
        __syncthreads();
    }

    #pragma unroll
    for (int r = 0; r < 10; r++)
        ibuf[(size_t)b * 2560 + r * 256 + t] = (t > 0) ? sm.buf[t-1][r] : 0.0f;
    if (t == 255) {
        #pragma unroll
        for (int r = 0; r < 10; r++) abuf[b * 10 + r] = s[r];
    }
}

// kB: one block per channel; KS scan of the channel's 256 block aggregates
// with Q_e = A^(8192*2^e) = P_{8+e}. Writes exclusive block prefixes.
__global__ __launch_bounds__(256) void kB(const float* __restrict__ mats,
                                          const float* __restrict__ abuf,
                                          float* __restrict__ bbuf) {
    __shared__ float Qf[800];
    __shared__ float buf[256][11];
    const int t = threadIdx.x, ch = blockIdx.x;
    const int g = ch * 256 + t;

    for (int i = t; i < 800; i += 256) Qf[i] = mats[800 + i];

    float v[10];
    #pragma unroll
    for (int r = 0; r < 10; r++) { v[r] = abuf[g * 10 + r]; buf[t][r] = v[r]; }
    __syncthreads();

    #pragma unroll 1
    for (int e = 0; e < 8; e++) {
        int src = t - (1 << e);
        int sc  = src < 0 ? 0 : src;
        float bs[10], nv[10];
        #pragma unroll
        for (int r = 0; r < 10; r++) { bs[r] = buf[sc][r]; nv[r] = v[r]; }
        matvec_tri(&Qf[e*100], bs, nv);
        __syncthreads();
        bool act = src >= 0;
        #pragma unroll
        for (int r = 0; r < 10; r++) { v[r] = act ? nv[r] : v[r]; buf[t][r] = v[r]; }
        __syncthreads();
    }

    #pragma unroll
    for (int r = 0; r < 10; r++)
        bbuf[g * 10 + r] = (t > 0) ? buf[t-1][r] : 0.0f;
}

// kC (light): init = ibuf[chunk] + A^(32*t)*bbuf[block] (8 triangular decomp
// matvecs), ONE cascade pass over the chunk staged as a full 32-sample LDS row
// ([256][33], odd stride), then FULL-LINE coop store: each store instruction
// writes 8 complete 128B lines (1 KB contiguous per wave). No partial-line
// writes anywhere (round-6-proven store path).
__global__ __launch_bounds__(256, 4) void kC(const float* __restrict__ x,
                                             const float* __restrict__ coef,
                                             const float* __restrict__ mats,
                                             const float* __restrict__ ibuf,
                                             const float* __restrict__ bbuf,
                                             float* __restrict__ out) {
    __shared__ float stage[256 * CSTRIDE];     // 33792 B: row = chunk (32 smp + pad)
    __shared__ float Mf[800];
    __shared__ float cfs[25];
    const int t = threadIdx.x, b = blockIdx.x;
    const int cb = t >> 2, q = t & 3;
    const float4* x4 = (const float4*)x + (size_t)b * 2048;
    float4* o4 = (float4*)out + (size_t)b * 2048;

    // issue all input loads up front
    float4 rr[4], rr2[4];
    #pragma unroll
    for (int k = 0; k < 4; k++) rr[k]  = x4[(cb + 64*k)*8 + q];
    #pragma unroll
    for (int k = 0; k < 4; k++) rr2[k] = x4[(cb + 64*k)*8 + 4 + q];

    float sp[10];
    #pragma unroll
    for (int r = 0; r < 10; r++) sp[r] = ibuf[(size_t)b * 2560 + r * 256 + t];
    float bp[10];
    #pragma unroll
    for (int r = 0; r < 10; r++) bp[r] = bbuf[b * 10 + r];

    for (int i = t; i < 800; i += 256) Mf[i] = mats[i];
    if (t < 25) cfs[t] = coef[t];

    // stage both windows: row = chunk, cols 0..15 (w0) and 16..31 (w1)
    #pragma unroll
    for (int k = 0; k < 4; k++) {
        int o = (cb + 64*k)*CSTRIDE + q*4;
        stage[o+0]=rr[k].x;  stage[o+1]=rr[k].y;
        stage[o+2]=rr[k].z;  stage[o+3]=rr[k].w;
        stage[o+16]=rr2[k].x; stage[o+17]=rr2[k].y;
        stage[o+18]=rr2[k].z; stage[o+19]=rr2[k].w;
    }
    __syncthreads();                           // B1: stage + Mf + cfs ready

    float cb0[5],cb1[5],cb2[5],ca1[5],ca2[5];
    #pragma unroll
    for (int i = 0; i < 5; i++) {
        cb0[i]=cfs[i*5+0]; cb1[i]=cfs[i*5+1]; cb2[i]=cfs[i*5+2];
        ca1[i]=cfs[i*5+3]; ca2[i]=cfs[i*5+4];
    }

    // binary decomposition: bp = A^(32*t) * Bpre
    #pragma unroll 1
    for (int d = 0; d < 8; d++) {
        float wv[10];
        #pragma unroll
        for (int r = 0; r < 10; r++) wv[r] = 0.0f;
        matvec_tri(&Mf[d*100], bp, wv);
        bool bit = (t >> d) & 1;
        #pragma unroll
        for (int r = 0; r < 10; r++) bp[r] = bit ? wv[r] : bp[r];
    }
    float s[10];
    #pragma unroll
    for (int r = 0; r < 10; r++) s[r] = sp[r] + bp[r];

    // single cascade pass over the full 32-sample row, in place
    {   float* row = stage + t*CSTRIDE;
        #pragma unroll
        for (int i = 0; i < 32; i++) row[i] = cascade5(cb0,cb1,cb2,ca1,ca2, s, row[i]);
    }
    __syncthreads();                           // B2: y complete

    // full-line coop store: chunk = c2 + 32*kk (row), piece p = t&7 (16B each);
    // lanes 0..7 cover one complete 128B line; 8 lines per instruction per wave.
    const int c2 = t >> 3, p = t & 7;
    #pragma unroll
    for (int kk = 0; kk < 8; kk++) {
        int chunk = c2 + 32*kk;
        const float* src = stage + chunk*CSTRIDE + p*4;
        o4[chunk*8 + p] = make_float4(src[0], src[1], src[2], src[3]);
    }
}

extern "C" void kernel_launch(void* const* d_in, const int* in_sizes, int n_in,
                              void* d_out, int out_size, void* d_ws, size_t ws_size,
                              hipStream_t stream) {
    const float* x   = (const float*)d_in[0];
    const float* eqp = (const float*)d_in[1];
    float* out = (float*)d_out;
    char* ws = (char*)d_ws;

    float* coef_f = (float*)ws;                              // 25 floats
    float* mats_f = (float*)(ws + 256);                      // 1600 floats
    float* ibuf   = (float*)(ws + 8192);                     // 2048*2560 fl = 20.97 MB
    float* abuf   = (float*)(ws + 8192 + 20971520);          // 2048*10 floats
    float* bbuf   = (float*)(ws + 8192 + 20971520 + 81920);  // 2048*10 floats

    hipLaunchKernelGGL(k0_setup, dim3(1), dim3(128), 0, stream, eqp, coef_f, mats_f);
    hipLaunchKernelGGL(kA, dim3(NBLK), dim3(THREADS), 0, stream, x, coef_f, mats_f, ibuf, abuf);
    hipLaunchKernelGGL(kB, dim3(8),    dim3(THREADS), 0, stream, mats_f, abuf, bbuf);
    hipLaunchKernelGGL(kC, dim3(NBLK), dim3(THREADS), 0, stream,
                       x, coef_f, mats_f, ibuf, bbuf, out);
}